// Round 3
// baseline (287.230 us; speedup 1.0000x reference)
//
#include <hip/hip_runtime.h>
#include <math.h>

// Problem constants (fixed by the reference): B=16, C=9, H=W=512.
#define NCLS 9
#define NB 16
#define HW (512 * 512)          // labels per sample = 262144
#define NBLK_HIST 512           // 32 hist blocks per sample
#define BLKS_PER_SAMPLE 32
#define NTHREADS 256
#define SCALE_BLOCKS 2048
#define N4 (NB * NCLS * HW / 4) // 9437184 float4s
#define STRIDE (SCALE_BLOCKS * NTHREADS)   // 524288 -> exactly 18 iters/thread

// ---------------------------------------------------------------------------
// Kernel 1: per-block partial histograms -> partial[512][9] (fully written,
// no zero-init, no atomics). 512 blocks x 256 threads; each thread consumes
// 32 labels via 8x int4 (8 loads in flight). Each block's 8192-label chunk
// lies inside one sample (262144/8192 = 32 blocks/sample).
// ---------------------------------------------------------------------------
__global__ void __launch_bounds__(256) hist_kernel(const int* __restrict__ labels,
                                                   int* __restrict__ partial) {
    const int tid = blockIdx.x * 256 + threadIdx.x;
    const int4* l4 = (const int4*)labels;
    const int base = tid * 8;           // int4 index

    int4 v[8];
#pragma unroll
    for (int j = 0; j < 8; ++j) v[j] = l4[base + j];

    int cnt[NCLS];
#pragma unroll
    for (int c = 0; c < NCLS; ++c) cnt[c] = 0;
#pragma unroll
    for (int j = 0; j < 8; ++j) {
#pragma unroll
        for (int c = 0; c < NCLS; ++c) {
            cnt[c] += (v[j].x == c) + (v[j].y == c) + (v[j].z == c) + (v[j].w == c);
        }
    }

    __shared__ int lds[4][NCLS];        // 4 waves per block
    const int wave = threadIdx.x >> 6;
    const int lane = threadIdx.x & 63;
#pragma unroll
    for (int c = 0; c < NCLS; ++c) {
        int s = cnt[c];
#pragma unroll
        for (int off = 32; off > 0; off >>= 1) s += __shfl_down(s, off);
        if (lane == 0) lds[wave][c] = s;
    }
    __syncthreads();
    if (threadIdx.x < NCLS) {
        const int c = threadIdx.x;
        partial[blockIdx.x * NCLS + c] =
            lds[0][c] + lds[1][c] + lds[2][c] + lds[3][c];
    }
}

// ---------------------------------------------------------------------------
// Kernel 2 (fused): reduce partials -> weights in LDS, then stream-scale.
// Weight math matches the numpy reference:
//   p = h/total; logh = (h>0) ? -log(p) : 0
//   mean/std over bins with h>0 (population variance, ddof=0)
//   weight = (logh != 0) ? (logh-mean)/std*0.1 + 1.0 : 1.0
// Stream phase: compile-time 18 trips = 3 batches x 6 float4 loads in flight.
// ---------------------------------------------------------------------------
__global__ void __launch_bounds__(256) fused_weight_scale_kernel(
        const int* __restrict__ partial,
        const float4* __restrict__ in,
        float4* __restrict__ out) {
    __shared__ float hsm[NB * NCLS];
    __shared__ float wsm[NB * NCLS];
    const int t = threadIdx.x;

    if (t < NB * NCLS) {
        const int b = t / NCLS;
        const int c = t % NCLS;
        const int* p = partial + b * (BLKS_PER_SAMPLE * NCLS) + c;
        int s = 0;
#pragma unroll
        for (int k = 0; k < BLKS_PER_SAMPLE; ++k) s += p[k * NCLS];
        hsm[t] = (float)s;
    }
    __syncthreads();

    if (t < NB * NCLS) {
        const int b = t / NCLS;
        const int c = t % NCLS;
        float h[NCLS];
        float total = 0.f;
#pragma unroll
        for (int k = 0; k < NCLS; ++k) {
            h[k] = hsm[b * NCLS + k];
            total += h[k];
        }
        float logh[NCLS];
        float cntbins = 0.f, sum = 0.f;
#pragma unroll
        for (int k = 0; k < NCLS; ++k) {
            float p = h[k] / total;
            float lg = (h[k] > 0.f) ? -logf(p) : 0.f;
            logh[k] = lg;
            if (h[k] > 0.f) { cntbins += 1.f; sum += lg; }
        }
        const float mean = sum / cntbins;
        float var = 0.f;
#pragma unroll
        for (int k = 0; k < NCLS; ++k) {
            if (h[k] > 0.f) {
                float d = logh[k] - mean;
                var += d * d;
            }
        }
        var /= cntbins;
        const float stdv = sqrtf(var);
        const float lc = logh[c];
        wsm[t] = (lc != 0.f) ? (lc - mean) / stdv * 0.1f + 1.0f : 1.0f;
    }
    __syncthreads();

    // Stream phase: exactly 18 float4s per thread (N4 == 18*STRIDE),
    // 3 batches of 6 loads each -> 6 outstanding 1KB wave-loads.
    const int tid = blockIdx.x * 256 + t;     // 0 .. STRIDE-1
#pragma unroll
    for (int bb = 0; bb < 3; ++bb) {
        const int i0 = tid + bb * 6 * STRIDE;
        float4 v[6];
#pragma unroll
        for (int j = 0; j < 6; ++j) v[j] = in[i0 + j * STRIDE];
        float w[6];
#pragma unroll
        for (int j = 0; j < 6; ++j) w[j] = wsm[(i0 + j * STRIDE) >> 16];
#pragma unroll
        for (int j = 0; j < 6; ++j) {
            v[j].x *= w[j]; v[j].y *= w[j]; v[j].z *= w[j]; v[j].w *= w[j];
            out[i0 + j * STRIDE] = v[j];
        }
    }
}

extern "C" void kernel_launch(void* const* d_in, const int* in_sizes, int n_in,
                              void* d_out, int out_size, void* d_ws, size_t ws_size,
                              hipStream_t stream) {
    const float* preds = (const float*)d_in[0];   // [16,9,512,512] f32
    const int* labels = (const int*)d_in[1];      // [16,512,512] i32
    float* out = (float*)d_out;

    // Workspace: partial[512][9] ints (fully overwritten each call -> no init)
    int* partial = (int*)d_ws;

    hist_kernel<<<NBLK_HIST, 256, 0, stream>>>(labels, partial);

    fused_weight_scale_kernel<<<SCALE_BLOCKS, 256, 0, stream>>>(
        partial, (const float4*)preds, (float4*)out);
}